// Round 1
// baseline (285.484 us; speedup 1.0000x reference)
//
#include <hip/hip_runtime.h>

// Problem constants (fixed by setup_inputs): B=4, C=8, H=W=1024.
#define B_   4
#define C_   8
#define LOGN 20              // log2(H*W)
#define NPOS (1u << LOGN)    // H*W = 1048576 spatial positions per (b,c)

// Kernel 1: each thread handles 4 consecutive spatial positions (float4).
// For each position: lse over the 8 channels (stride NPOS floats apart),
// accumulate sum_c cw[c] * t[c] * (o[c] - lse). Block partial -> partials[].
__global__ __launch_bounds__(256) void ce_partial_kernel(
    const float* __restrict__ outs,
    const float* __restrict__ targets,
    const float* __restrict__ cw,
    const int*   __restrict__ flag_p,
    float* __restrict__ partials,
    int nvec)  // number of float4 positions = B*NPOS/4
{
    const int flag = *flag_p;            // logits_input (uniform)
    float w[C_];
#pragma unroll
    for (int c = 0; c < C_; ++c) w[c] = cw[c];   // uniform address -> scalar loads

    float acc = 0.0f;
    const int stride = gridDim.x * blockDim.x;
    for (int i = blockIdx.x * blockDim.x + threadIdx.x; i < nvec; i += stride) {
        const int p = i << 2;                    // scalar position index in [0, B*NPOS)
        const int b = p >> LOGN;                 // batch
        const int n = p & (NPOS - 1);            // spatial offset (multiple of 4 -> 16B aligned)
        const size_t base = ((size_t)(b * C_) << LOGN) + (size_t)n;
        const float4* __restrict__ ob = (const float4*)(outs    + base);
        const float4* __restrict__ tb = (const float4*)(targets + base);

        float4 o[C_], t[C_];
#pragma unroll
        for (int c = 0; c < C_; ++c) {
            o[c] = ob[(size_t)c << (LOGN - 2)];  // channel stride NPOS floats = NPOS/4 float4
            t[c] = tb[(size_t)c << (LOGN - 2)];
        }

#pragma unroll
        for (int j = 0; j < 4; ++j) {
            float oj[C_], tj[C_];
#pragma unroll
            for (int c = 0; c < C_; ++c) {
                oj[c] = ((const float*)&o[c])[j];
                tj[c] = ((const float*)&t[c])[j];
            }
            float lse = 0.0f;
            if (flag) {                          // wave-uniform branch
                float m = oj[0];
#pragma unroll
                for (int c = 1; c < C_; ++c) m = fmaxf(m, oj[c]);
                float s = 0.0f;
#pragma unroll
                for (int c = 0; c < C_; ++c) s += __expf(oj[c] - m);
                lse = m + __logf(s);
            }
#pragma unroll
            for (int c = 0; c < C_; ++c) acc += w[c] * tj[c] * (oj[c] - lse);
        }
    }

    // wave (64-lane) shuffle reduction
#pragma unroll
    for (int off = 32; off > 0; off >>= 1) acc += __shfl_down(acc, off, 64);

    __shared__ float sm[4];
    const int lane = threadIdx.x & 63;
    const int wave = threadIdx.x >> 6;
    if (lane == 0) sm[wave] = acc;
    __syncthreads();
    if (threadIdx.x == 0) {
        partials[blockIdx.x] = sm[0] + sm[1] + sm[2] + sm[3];
    }
}

// Kernel 2: reduce per-block partials, scale, write the scalar loss.
__global__ __launch_bounds__(256) void ce_final_kernel(
    const float* __restrict__ partials, int nblocks,
    float* __restrict__ out, float scale)
{
    float acc = 0.0f;
    for (int i = threadIdx.x; i < nblocks; i += 256) acc += partials[i];
#pragma unroll
    for (int off = 32; off > 0; off >>= 1) acc += __shfl_down(acc, off, 64);
    __shared__ float sm[4];
    const int lane = threadIdx.x & 63;
    const int wave = threadIdx.x >> 6;
    if (lane == 0) sm[wave] = acc;
    __syncthreads();
    if (threadIdx.x == 0) {
        out[0] = (sm[0] + sm[1] + sm[2] + sm[3]) * scale;
    }
}

extern "C" void kernel_launch(void* const* d_in, const int* in_sizes, int n_in,
                              void* d_out, int out_size, void* d_ws, size_t ws_size,
                              hipStream_t stream) {
    const float* outs    = (const float*)d_in[0];
    const float* targets = (const float*)d_in[1];
    const float* cw      = (const float*)d_in[2];
    const int*   flag    = (const int*)d_in[3];
    float* partials = (float*)d_ws;              // 1024 floats of scratch
    float* out      = (float*)d_out;

    const int nvec   = (B_ * (int)NPOS) / 4;     // 1,048,576 float4 positions
    const int blocks = 1024;                     // 16 waves/CU, 4 iters/thread

    ce_partial_kernel<<<blocks, 256, 0, stream>>>(outs, targets, cw, flag, partials, nvec);

    const float scale = -1.0f / (float)((size_t)B_ * C_ * NPOS);
    ce_final_kernel<<<1, 256, 0, stream>>>(partials, blocks, out, scale);
}

// Round 2
// 277.068 us; speedup vs baseline: 1.0304x; 1.0304x over previous
//
#include <hip/hip_runtime.h>

// Problem constants (fixed by setup_inputs): B=4, C=8, H=W=1024.
#define B_   4
#define C_   8
#define LOGN 20              // log2(H*W)
#define NPOS (1u << LOGN)    // H*W = 1048576 spatial positions per (b,c)

// Kernel 1: one thread = one float4 group of 4 consecutive spatial positions.
// Loads 8 channels x {outs,targets} (16 x dwordx4, all independent), computes
// lse over channels per position, accumulates sum_c w[c]*t[c]*(o[c]-lse).
// Identity used: sum_c w*t*(o-lse) = (sum_c w*t*o) - lse*(sum_c w*t)
// so t[] is consumed as it arrives; only o[] must persist for the lse pass.
__global__ __launch_bounds__(256) void ce_partial_kernel(
    const float* __restrict__ outs,
    const float* __restrict__ targets,
    const float* __restrict__ cw,
    const int*   __restrict__ flag_p,
    float* __restrict__ partials,
    int nvec)  // number of float4 positions = B*NPOS/4
{
    const int flag = *flag_p;            // logits_input (uniform)
    float w[C_];
#pragma unroll
    for (int c = 0; c < C_; ++c) w[c] = cw[c];   // uniform -> scalar loads

    float acc = 0.0f;
    const int i = blockIdx.x * blockDim.x + threadIdx.x;
    if (i < nvec) {
        const int p = i << 2;                    // scalar position index
        const int b = p >> LOGN;                 // batch
        const int n = p & (NPOS - 1);            // spatial offset (16B aligned)
        const size_t base = ((size_t)(b * C_) << LOGN) + (size_t)n;
        const float4* __restrict__ ob = (const float4*)(outs    + base);
        const float4* __restrict__ tb = (const float4*)(targets + base);

        float4 o[C_], t[C_];
#pragma unroll
        for (int c = 0; c < C_; ++c) {
            o[c] = ob[(size_t)c << (LOGN - 2)];  // channel stride = NPOS/4 float4
            t[c] = tb[(size_t)c << (LOGN - 2)];
        }

        // Incremental pass: consume t[c] immediately; track per-position max.
        float4 dot    = make_float4(0.f, 0.f, 0.f, 0.f);  // sum_c w*t*o
        float4 sum_wt = make_float4(0.f, 0.f, 0.f, 0.f);  // sum_c w*t
        float4 mx     = o[0];
#pragma unroll
        for (int c = 0; c < C_; ++c) {
            const float4 oc = o[c], tc = t[c];
            dot.x += w[c] * tc.x * oc.x;  sum_wt.x += w[c] * tc.x;
            dot.y += w[c] * tc.y * oc.y;  sum_wt.y += w[c] * tc.y;
            dot.z += w[c] * tc.z * oc.z;  sum_wt.z += w[c] * tc.z;
            dot.w += w[c] * tc.w * oc.w;  sum_wt.w += w[c] * tc.w;
            mx.x = fmaxf(mx.x, oc.x); mx.y = fmaxf(mx.y, oc.y);
            mx.z = fmaxf(mx.z, oc.z); mx.w = fmaxf(mx.w, oc.w);
        }

        float4 lse = make_float4(0.f, 0.f, 0.f, 0.f);
        if (flag) {                              // wave-uniform branch
            float4 s = make_float4(0.f, 0.f, 0.f, 0.f);
#pragma unroll
            for (int c = 0; c < C_; ++c) {
                s.x += __expf(o[c].x - mx.x);
                s.y += __expf(o[c].y - mx.y);
                s.z += __expf(o[c].z - mx.z);
                s.w += __expf(o[c].w - mx.w);
            }
            lse.x = mx.x + __logf(s.x);
            lse.y = mx.y + __logf(s.y);
            lse.z = mx.z + __logf(s.z);
            lse.w = mx.w + __logf(s.w);
        }
        acc = (dot.x - lse.x * sum_wt.x) + (dot.y - lse.y * sum_wt.y)
            + (dot.z - lse.z * sum_wt.z) + (dot.w - lse.w * sum_wt.w);
    }

    // wave (64-lane) shuffle reduction
#pragma unroll
    for (int off = 32; off > 0; off >>= 1) acc += __shfl_down(acc, off, 64);

    __shared__ float sm[4];
    const int lane = threadIdx.x & 63;
    const int wave = threadIdx.x >> 6;
    if (lane == 0) sm[wave] = acc;
    __syncthreads();
    if (threadIdx.x == 0) {
        partials[blockIdx.x] = sm[0] + sm[1] + sm[2] + sm[3];
    }
}

// Kernel 2: reduce per-block partials, scale, write the scalar loss.
__global__ __launch_bounds__(256) void ce_final_kernel(
    const float* __restrict__ partials, int nblocks,
    float* __restrict__ out, float scale)
{
    float acc = 0.0f;
    for (int i = threadIdx.x; i < nblocks; i += 256) acc += partials[i];
#pragma unroll
    for (int off = 32; off > 0; off >>= 1) acc += __shfl_down(acc, off, 64);
    __shared__ float sm[4];
    const int lane = threadIdx.x & 63;
    const int wave = threadIdx.x >> 6;
    if (lane == 0) sm[wave] = acc;
    __syncthreads();
    if (threadIdx.x == 0) {
        out[0] = (sm[0] + sm[1] + sm[2] + sm[3]) * scale;
    }
}

extern "C" void kernel_launch(void* const* d_in, const int* in_sizes, int n_in,
                              void* d_out, int out_size, void* d_ws, size_t ws_size,
                              hipStream_t stream) {
    const float* outs    = (const float*)d_in[0];
    const float* targets = (const float*)d_in[1];
    const float* cw      = (const float*)d_in[2];
    const int*   flag    = (const int*)d_in[3];
    float* partials = (float*)d_ws;              // 4096 floats of scratch
    float* out      = (float*)d_out;

    const int nvec   = (B_ * (int)NPOS) / 4;     // 1,048,576 float4 positions
    const int blocks = nvec / 256;               // 4096 blocks, 1 trip/thread

    ce_partial_kernel<<<blocks, 256, 0, stream>>>(outs, targets, cw, flag, partials, nvec);

    const float scale = -1.0f / (float)((size_t)B_ * C_ * NPOS);
    ce_final_kernel<<<1, 256, 0, stream>>>(partials, blocks, out, scale);
}

// Round 4
// 257.890 us; speedup vs baseline: 1.1070x; 1.0744x over previous
//
#include <hip/hip_runtime.h>

// Problem constants (fixed by setup_inputs): B=4, C=8, H=W=1024.
#define B_   4
#define C_   8
#define LOGN 20              // log2(H*W)
#define NPOS (1u << LOGN)    // H*W = 1048576 spatial positions per (b,c)

// Native clang vector type: __builtin_nontemporal_load requires a pointer to
// scalar/vector-of-scalar, not HIP's HIP_vector_type class.
typedef float v4f __attribute__((ext_vector_type(4)));

// Kernel 1: one thread = one float4 group of 4 consecutive spatial positions.
// All 16 channel-stream loads (8 x outs, 8 x targets) are issued nontemporal
// (streaming, L1-bypass: the 4 MiB channel stride makes all 16 streams alias
// the same L1 set) and are fenced behind a sched_barrier so the compiler
// cannot interleave uses -> one waitcnt, 16 loads in flight per wave.
__global__ __launch_bounds__(256) void ce_partial_kernel(
    const float* __restrict__ outs,
    const float* __restrict__ targets,
    const float* __restrict__ cw,
    const int*   __restrict__ flag_p,
    float* __restrict__ partials,
    int nvec)  // number of float4 positions = B*NPOS/4
{
    const int flag = *flag_p;            // logits_input (uniform)
    float w[C_];
#pragma unroll
    for (int c = 0; c < C_; ++c) w[c] = cw[c];   // uniform -> scalar loads

    float acc = 0.0f;
    const int i = blockIdx.x * blockDim.x + threadIdx.x;
    if (i < nvec) {
        const int p = i << 2;                    // scalar position index
        const int b = p >> LOGN;                 // batch
        const int n = p & (NPOS - 1);            // spatial offset (16B aligned)
        const size_t base = ((size_t)(b * C_) << LOGN) + (size_t)n;
        const v4f* __restrict__ ob = (const v4f*)(outs    + base);
        const v4f* __restrict__ tb = (const v4f*)(targets + base);

        v4f o[C_], t[C_];
#pragma unroll
        for (int c = 0; c < C_; ++c) {
            o[c] = __builtin_nontemporal_load(ob + ((size_t)c << (LOGN - 2)));
            t[c] = __builtin_nontemporal_load(tb + ((size_t)c << (LOGN - 2)));
        }
        // Keep all 16 loads issued before any consumer is scheduled.
        __builtin_amdgcn_sched_barrier(0);

        v4f dot    = (v4f)(0.f);                 // sum_c w*t*o
        v4f sum_wt = (v4f)(0.f);                 // sum_c w*t
        v4f mx     = o[0];
#pragma unroll
        for (int c = 0; c < C_; ++c) {
            const v4f oc = o[c], tc = t[c];
            const v4f wt = w[c] * tc;
            dot    += wt * oc;
            sum_wt += wt;
            mx.x = fmaxf(mx.x, oc.x); mx.y = fmaxf(mx.y, oc.y);
            mx.z = fmaxf(mx.z, oc.z); mx.w = fmaxf(mx.w, oc.w);
        }

        v4f lse = (v4f)(0.f);
        if (flag) {                              // wave-uniform branch
            v4f s = (v4f)(0.f);
#pragma unroll
            for (int c = 0; c < C_; ++c) {
                s.x += __expf(o[c].x - mx.x);
                s.y += __expf(o[c].y - mx.y);
                s.z += __expf(o[c].z - mx.z);
                s.w += __expf(o[c].w - mx.w);
            }
            lse.x = mx.x + __logf(s.x);
            lse.y = mx.y + __logf(s.y);
            lse.z = mx.z + __logf(s.z);
            lse.w = mx.w + __logf(s.w);
        }
        const v4f r = dot - lse * sum_wt;
        acc = r.x + r.y + r.z + r.w;
    }

    // wave (64-lane) shuffle reduction
#pragma unroll
    for (int off = 32; off > 0; off >>= 1) acc += __shfl_down(acc, off, 64);

    __shared__ float sm[4];
    const int lane = threadIdx.x & 63;
    const int wave = threadIdx.x >> 6;
    if (lane == 0) sm[wave] = acc;
    __syncthreads();
    if (threadIdx.x == 0) {
        partials[blockIdx.x] = sm[0] + sm[1] + sm[2] + sm[3];
    }
}

// Kernel 2: reduce per-block partials, scale, write the scalar loss.
__global__ __launch_bounds__(256) void ce_final_kernel(
    const float* __restrict__ partials, int nblocks,
    float* __restrict__ out, float scale)
{
    float acc = 0.0f;
    for (int i = threadIdx.x; i < nblocks; i += 256) acc += partials[i];
#pragma unroll
    for (int off = 32; off > 0; off >>= 1) acc += __shfl_down(acc, off, 64);
    __shared__ float sm[4];
    const int lane = threadIdx.x & 63;
    const int wave = threadIdx.x >> 6;
    if (lane == 0) sm[wave] = acc;
    __syncthreads();
    if (threadIdx.x == 0) {
        out[0] = (sm[0] + sm[1] + sm[2] + sm[3]) * scale;
    }
}

extern "C" void kernel_launch(void* const* d_in, const int* in_sizes, int n_in,
                              void* d_out, int out_size, void* d_ws, size_t ws_size,
                              hipStream_t stream) {
    const float* outs    = (const float*)d_in[0];
    const float* targets = (const float*)d_in[1];
    const float* cw      = (const float*)d_in[2];
    const int*   flag    = (const int*)d_in[3];
    float* partials = (float*)d_ws;              // 4096 floats of scratch
    float* out      = (float*)d_out;

    const int nvec   = (B_ * (int)NPOS) / 4;     // 1,048,576 float4 positions
    const int blocks = nvec / 256;               // 4096 blocks, 1 trip/thread

    ce_partial_kernel<<<blocks, 256, 0, stream>>>(outs, targets, cw, flag, partials, nvec);

    const float scale = -1.0f / (float)((size_t)B_ * C_ * NPOS);
    ce_final_kernel<<<1, 256, 0, stream>>>(partials, blocks, out, scale);
}